// Round 5
// baseline (170.143 us; speedup 1.0000x reference)
//
#include <hip/hip_runtime.h>
#include <math.h>
#include <stdint.h>

typedef short bf16x8 __attribute__((ext_vector_type(8)));
typedef float f32x16 __attribute__((ext_vector_type(16)));
typedef unsigned short ushort_t;

// ---------------- workspace layout (float offsets) ----------------
#define WS_POOLED 0
#define WS_CIN    2048
#define WS_COUT   4096
#define WS_SP9    6144
#define WS_K4     6432
#define WS_WF     8192   // ushort wfb: 32*9*64*64 = 2.36 MB

static __device__ __forceinline__ unsigned f2bf(float f) {
  unsigned u = __builtin_bit_cast(unsigned, f);
  return (u + 0x7FFFu + ((u >> 16) & 1u)) >> 16;   // RNE
}
static __device__ __forceinline__ unsigned pk2(float a, float b) {
  return f2bf(a) | (f2bf(b) << 16);
}

// ---------------- 1) global average pool ----------------
__global__ __launch_bounds__(256) void pool_kernel(const float* __restrict__ x,
                                                   float* __restrict__ pooled) {
  const int bc = blockIdx.x;
  const int tid = threadIdx.x;
  const float4* p = (const float4*)(x + (size_t)bc * 16384);
  float s = 0.f;
  for (int j = tid; j < 4096; j += 256) {
    float4 v = p[j];
    s += (v.x + v.y) + (v.z + v.w);
  }
#pragma unroll
  for (int off = 32; off > 0; off >>= 1) s += __shfl_down(s, off, 64);
  __shared__ float red[4];
  if ((tid & 63) == 0) red[tid >> 6] = s;
  __syncthreads();
  if (tid == 0) pooled[bc] = (red[0] + red[1] + red[2] + red[3]) * (1.f / 16384.f);
}

// ---------------- 2) attention chain, one block per batch ----------------
__global__ __launch_bounds__(128) void att_kernel(
    const float* __restrict__ pooled,
    const float* __restrict__ fc_w, const float* __restrict__ ch_w, const float* __restrict__ ch_b,
    const float* __restrict__ f_w,  const float* __restrict__ f_b,
    const float* __restrict__ sp_w, const float* __restrict__ sp_b,
    const float* __restrict__ k_w,  const float* __restrict__ k_b,
    const float* __restrict__ fus_w1, const float* __restrict__ fus_b1,
    const float* __restrict__ fus_w2, const float* __restrict__ fus_b2,
    float* __restrict__ o_cin, float* __restrict__ o_cout,
    float* __restrict__ o_sp9, float* __restrict__ o_k4) {
  const int b = blockIdx.x;
  const int t = threadIdx.x;
  __shared__ float s_pool[64], s_a[16], s_att[128], s_sp[9], s_k[4], s_h[8],
      s_att2[128], s_red[2], s_w12[2];

  if (t < 64) s_pool[t] = pooled[b * 64 + t];
  __syncthreads();

  if (t < 16) {
    float s = 0.f;
    for (int c = 0; c < 64; ++c) s += s_pool[c] * fc_w[t * 64 + c];
    s_a[t] = fmaxf(s, 0.f);
  }
  __syncthreads();

  if (t < 64) {
    float s = ch_b[t];
    for (int j = 0; j < 16; ++j) s += s_a[j] * ch_w[t * 16 + j];
    s_att[t] = 1.f / (1.f + expf(-s));
  } else {
    const int o = t - 64;
    float s = f_b[o];
    for (int j = 0; j < 16; ++j) s += s_a[j] * f_w[o * 16 + j];
    s_att[t] = 1.f / (1.f + expf(-s));
  }
  if (t < 9) {
    float s = sp_b[t];
    for (int j = 0; j < 16; ++j) s += s_a[j] * sp_w[t * 16 + j];
    s_sp[t] = 1.f / (1.f + expf(-s));
  }
  if (t < 4) {
    float s = k_b[t];
    for (int j = 0; j < 16; ++j) s += s_a[j] * k_w[t * 16 + j];
    s_k[t] = s;
  }
  __syncthreads();

  if (t < 8) {
    float s = fus_b1[t];
    for (int c = 0; c < 128; ++c) s += s_att[c] * fus_w1[t * 128 + c];
    s_h[t] = fmaxf(s, 0.f);
  }
  if (t == 127) {
    float m = fmaxf(fmaxf(s_k[0], s_k[1]), fmaxf(s_k[2], s_k[3]));
    float e0 = expf(s_k[0] - m), e1 = expf(s_k[1] - m);
    float e2 = expf(s_k[2] - m), e3 = expf(s_k[3] - m);
    float inv = 1.f / (e0 + e1 + e2 + e3);
    s_k[0] = e0 * inv; s_k[1] = e1 * inv; s_k[2] = e2 * inv; s_k[3] = e3 * inv;
  }
  __syncthreads();

  {
    float s = fus_b2[t];
    for (int j = 0; j < 8; ++j) s += s_h[j] * fus_w2[t * 8 + j];
    s_att2[t] = 1.f / (1.f + expf(-s));
  }
  __syncthreads();

  if (t < 2) {
    float s = 0.f;
    for (int c = 0; c < 64; ++c) s += s_att2[t * 64 + c];
    s_red[t] = s;
  }
  __syncthreads();
  if (t == 0) {
    float m = fmaxf(s_red[0], s_red[1]);
    float e1 = expf(s_red[0] - m), e2 = expf(s_red[1] - m);
    float inv = 1.f / (e1 + e2);
    s_w12[0] = e1 * inv;
    s_w12[1] = e2 * inv;
  }
  __syncthreads();

  if (t < 64) {
    o_cin[b * 64 + t]  = s_w12[0] * s_att[t];
    o_cout[b * 64 + t] = s_w12[1] * s_att[64 + t];
  }
  if (t < 9) o_sp9[b * 9 + t] = s_sp[t];
  if (t < 4) o_k4[b * 4 + t] = s_k[t];
}

// ---------------- 3) fused per-sample weight -> bf16 [b][pq][o][i] ----------------
__global__ __launch_bounds__(256) void wf_kernel(const float* __restrict__ weight,
                                                 const float* __restrict__ cin,
                                                 const float* __restrict__ cout_,
                                                 const float* __restrict__ sp9,
                                                 const float* __restrict__ k4,
                                                 ushort_t* __restrict__ wfb) {
  const int bo = blockIdx.x;              // b*64 + o
  const int b = bo >> 6, o = bo & 63;
  const float co = cout_[b * 64 + o];
  const float k0 = k4[b * 4 + 0], k1 = k4[b * 4 + 1];
  const float k2 = k4[b * 4 + 2], k3 = k4[b * 4 + 3];
  for (int idx = threadIdx.x; idx < 576; idx += 256) {
    const int pq = idx >> 6, i = idx & 63;
    const size_t wi = ((size_t)o * 64 + i) * 9 + pq;
    float s = k0 * weight[wi] + k1 * weight[36864 + wi] +
              k2 * weight[73728 + wi] + k3 * weight[110592 + wi];
    float v = co * sp9[b * 9 + pq] * cin[b * 64 + i] * s;
    wfb[((size_t)(b * 9 + pq) * 64 + o) * 64 + i] = (ushort_t)f2bf(v);
  }
}

// ---------------- 4) implicit-GEMM conv, double-buffered, 64-oc waves ----------------
// block: 256 thr (4 waves), one batch, 4 output rows x 128 cols, all 64 oc.
// wave: 1 row x 128 cols x 64 oc -> 8 C-frags (acc[2][4]).
// LDS: 2 x [pix=6*136][16 ci] bf16, XOR swizzle byte^=((line&7)<<4), line=pix>>2.
#define CONV_BUF_BYTES 26112
__global__ __launch_bounds__(256, 2) void conv_kernel(const float* __restrict__ x,
                                                      const ushort_t* __restrict__ wfb,
                                                      float* __restrict__ out) {
  const int b  = blockIdx.x >> 5;
  const int h0 = (blockIdx.x & 31) << 2;
  const int tid = threadIdx.x;
  const int lane = tid & 63;
  const int wv  = tid >> 6;             // wave -> output row h0+wv
  const int l31 = lane & 31;
  const int hi  = lane >> 5;

  __shared__ __align__(16) short sx[2 * 816 * 16];   // 52224 B

  f32x16 acc[2][4];
#pragma unroll
  for (int of = 0; of < 2; ++of)
#pragma unroll
    for (int nt = 0; nt < 4; ++nt)
#pragma unroll
      for (int r = 0; r < 16; ++r) acc[of][nt][r] = 0.f;

  const ushort_t* wfb_b = wfb + (size_t)b * 9 * 64 * 64;

  // staging slot: 204 = 6 rows x 34 f4-cols; thread owns all 16 ci of its slot
  const bool sact = tid < 204;
  const int sr = tid / 34, sc = tid % 34;
  const int gr  = h0 - 1 + sr;
  const int gcb = sc * 4 - 4;
  const bool inb = sact && ((unsigned)gr < 128u) && ((unsigned)gcb < 128u);
  const int pixb = sr * 136 + sc * 4;
  const int key = (tid & 7) << 4;       // line = pixb>>2 = tid
  const float* xrow = x + ((size_t)b * 64) * 16384 + gr * 128 + gcb;

#define PACK_WRITE(BUFB)                                                        \
  do {                                                                          \
    _Pragma("unroll") for (int oct = 0; oct < 2; ++oct) {                       \
      _Pragma("unroll") for (int j = 0; j < 4; ++j) {                           \
        uint4 u;                                                                \
        u.x = pk2(((const float*)&v[oct * 8 + 0])[j], ((const float*)&v[oct * 8 + 1])[j]); \
        u.y = pk2(((const float*)&v[oct * 8 + 2])[j], ((const float*)&v[oct * 8 + 3])[j]); \
        u.z = pk2(((const float*)&v[oct * 8 + 4])[j], ((const float*)&v[oct * 8 + 5])[j]); \
        u.w = pk2(((const float*)&v[oct * 8 + 6])[j], ((const float*)&v[oct * 8 + 7])[j]); \
        *(uint4*)((char*)sx + (BUFB) + ((((pixb + j) * 32) + oct * 16) ^ key)) = u; \
      }                                                                         \
    }                                                                           \
  } while (0)

  // zero-fill OOB slots once (both buffers)
  if (sact && !inb) {
    const uint4 z = make_uint4(0u, 0u, 0u, 0u);
#pragma unroll
    for (int buf = 0; buf < 2; ++buf)
#pragma unroll
      for (int oct = 0; oct < 2; ++oct)
#pragma unroll
        for (int j = 0; j < 4; ++j)
          *(uint4*)((char*)sx + buf * CONV_BUF_BYTES +
                    ((((pixb + j) * 32) + oct * 16) ^ key)) = z;
  }

  float4 v[16];
  // prologue: chunk 0 -> buf 0
  if (inb) {
#pragma unroll
    for (int ci = 0; ci < 16; ++ci) v[ci] = *(const float4*)(xrow + (size_t)ci * 16384);
    PACK_WRITE(0);
  }
  __syncthreads();

#pragma unroll
  for (int ch = 0; ch < 4; ++ch) {
    const int c0 = ch * 16;
    // issue next chunk's loads early (latency hides under compute)
    if (ch < 3 && inb) {
#pragma unroll
      for (int ci = 0; ci < 16; ++ci)
        v[ci] = *(const float4*)(xrow + (size_t)(c0 + 16 + ci) * 16384);
    }
    const int bufb = (ch & 1) * CONV_BUF_BYTES;
#pragma unroll
    for (int p = 0; p < 3; ++p) {
#pragma unroll
      for (int q = 0; q < 3; ++q) {
        const int tap = p * 3 + q;
        bf16x8 af0 = *(const bf16x8*)(wfb_b + (tap * 64 + l31) * 64 + c0 + hi * 8);
        bf16x8 af1 = *(const bf16x8*)(wfb_b + (tap * 64 + 32 + l31) * 64 + c0 + hi * 8);
#pragma unroll
        for (int nt = 0; nt < 4; ++nt) {
          const int pix = (wv + p) * 136 + 3 + q + nt * 32 + l31;
          const int boff = bufb + ((pix * 32 + hi * 16) ^ (((pix >> 2) & 7) << 4));
          bf16x8 bf = *(const bf16x8*)((const char*)sx + boff);
          acc[0][nt] = __builtin_amdgcn_mfma_f32_32x32x16_bf16(af0, bf, acc[0][nt], 0, 0, 0);
          acc[1][nt] = __builtin_amdgcn_mfma_f32_32x32x16_bf16(af1, bf, acc[1][nt], 0, 0, 0);
        }
      }
    }
    if (ch < 3) {
      if (inb) PACK_WRITE(((ch + 1) & 1) * CONV_BUF_BYTES);
      __syncthreads();
    }
  }

  const int h = h0 + wv;
#pragma unroll
  for (int of = 0; of < 2; ++of) {
#pragma unroll
    for (int nt = 0; nt < 4; ++nt) {
      const int col = nt * 32 + l31;
#pragma unroll
      for (int reg = 0; reg < 16; ++reg) {
        const int o = of * 32 + (reg & 3) + ((reg >> 2) << 3) + (hi << 2);
        out[(((size_t)(b * 64 + o)) * 128 + h) * 128 + col] = acc[of][nt][reg];
      }
    }
  }
#undef PACK_WRITE
}

extern "C" void kernel_launch(void* const* d_in, const int* in_sizes, int n_in,
                              void* d_out, int out_size, void* d_ws, size_t ws_size,
                              hipStream_t stream) {
  const float* x      = (const float*)d_in[0];
  const float* fc_w   = (const float*)d_in[1];
  const float* ch_w   = (const float*)d_in[2];
  const float* ch_b   = (const float*)d_in[3];
  const float* f_w    = (const float*)d_in[4];
  const float* f_b    = (const float*)d_in[5];
  const float* sp_w   = (const float*)d_in[6];
  const float* sp_b   = (const float*)d_in[7];
  const float* k_w    = (const float*)d_in[8];
  const float* k_b    = (const float*)d_in[9];
  const float* fus_w1 = (const float*)d_in[10];
  const float* fus_b1 = (const float*)d_in[11];
  const float* fus_w2 = (const float*)d_in[12];
  const float* fus_b2 = (const float*)d_in[13];
  const float* weight = (const float*)d_in[14];
  float* ws  = (float*)d_ws;
  float* out = (float*)d_out;
  ushort_t* wfb = (ushort_t*)(ws + WS_WF);

  pool_kernel<<<2048, 256, 0, stream>>>(x, ws + WS_POOLED);
  att_kernel<<<32, 128, 0, stream>>>(ws + WS_POOLED, fc_w, ch_w, ch_b, f_w, f_b,
                                     sp_w, sp_b, k_w, k_b, fus_w1, fus_b1,
                                     fus_w2, fus_b2, ws + WS_CIN, ws + WS_COUT,
                                     ws + WS_SP9, ws + WS_K4);
  wf_kernel<<<2048, 256, 0, stream>>>(weight, ws + WS_CIN, ws + WS_COUT,
                                      ws + WS_SP9, ws + WS_K4, wfb);
  conv_kernel<<<1024, 256, 0, stream>>>(x, wfb, out);
}

// Round 6
// 168.926 us; speedup vs baseline: 1.0072x; 1.0072x over previous
//
#include <hip/hip_runtime.h>
#include <math.h>
#include <stdint.h>

typedef short bf16x8 __attribute__((ext_vector_type(8)));
typedef float f32x16 __attribute__((ext_vector_type(16)));
typedef unsigned short ushort_t;

// ---------------- workspace layout (float offsets) ----------------
#define WS_POOLED 0
#define WS_CIN    2048
#define WS_COUT   4096
#define WS_SP9    6144
#define WS_K4     6432
#define WS_WF     8192   // ushort wfb: 32*9*64*64 = 2.36 MB

static __device__ __forceinline__ unsigned f2bf(float f) {
  unsigned u = __builtin_bit_cast(unsigned, f);
  return (u + 0x7FFFu + ((u >> 16) & 1u)) >> 16;   // RNE
}
static __device__ __forceinline__ unsigned pk2(float a, float b) {
  return f2bf(a) | (f2bf(b) << 16);
}

// ---------------- 1) global average pool ----------------
__global__ __launch_bounds__(256) void pool_kernel(const float* __restrict__ x,
                                                   float* __restrict__ pooled) {
  const int bc = blockIdx.x;
  const int tid = threadIdx.x;
  const float4* p = (const float4*)(x + (size_t)bc * 16384);
  float s = 0.f;
  for (int j = tid; j < 4096; j += 256) {
    float4 v = p[j];
    s += (v.x + v.y) + (v.z + v.w);
  }
#pragma unroll
  for (int off = 32; off > 0; off >>= 1) s += __shfl_down(s, off, 64);
  __shared__ float red[4];
  if ((tid & 63) == 0) red[tid >> 6] = s;
  __syncthreads();
  if (tid == 0) pooled[bc] = (red[0] + red[1] + red[2] + red[3]) * (1.f / 16384.f);
}

// ---------------- 2) attention chain, one block per batch ----------------
__global__ __launch_bounds__(128) void att_kernel(
    const float* __restrict__ pooled,
    const float* __restrict__ fc_w, const float* __restrict__ ch_w, const float* __restrict__ ch_b,
    const float* __restrict__ f_w,  const float* __restrict__ f_b,
    const float* __restrict__ sp_w, const float* __restrict__ sp_b,
    const float* __restrict__ k_w,  const float* __restrict__ k_b,
    const float* __restrict__ fus_w1, const float* __restrict__ fus_b1,
    const float* __restrict__ fus_w2, const float* __restrict__ fus_b2,
    float* __restrict__ o_cin, float* __restrict__ o_cout,
    float* __restrict__ o_sp9, float* __restrict__ o_k4) {
  const int b = blockIdx.x;
  const int t = threadIdx.x;
  __shared__ float s_pool[64], s_a[16], s_att[128], s_sp[9], s_k[4], s_h[8],
      s_att2[128], s_red[2], s_w12[2];

  if (t < 64) s_pool[t] = pooled[b * 64 + t];
  __syncthreads();

  if (t < 16) {
    float s = 0.f;
    for (int c = 0; c < 64; ++c) s += s_pool[c] * fc_w[t * 64 + c];
    s_a[t] = fmaxf(s, 0.f);
  }
  __syncthreads();

  if (t < 64) {
    float s = ch_b[t];
    for (int j = 0; j < 16; ++j) s += s_a[j] * ch_w[t * 16 + j];
    s_att[t] = 1.f / (1.f + expf(-s));
  } else {
    const int o = t - 64;
    float s = f_b[o];
    for (int j = 0; j < 16; ++j) s += s_a[j] * f_w[o * 16 + j];
    s_att[t] = 1.f / (1.f + expf(-s));
  }
  if (t < 9) {
    float s = sp_b[t];
    for (int j = 0; j < 16; ++j) s += s_a[j] * sp_w[t * 16 + j];
    s_sp[t] = 1.f / (1.f + expf(-s));
  }
  if (t < 4) {
    float s = k_b[t];
    for (int j = 0; j < 16; ++j) s += s_a[j] * k_w[t * 16 + j];
    s_k[t] = s;
  }
  __syncthreads();

  if (t < 8) {
    float s = fus_b1[t];
    for (int c = 0; c < 128; ++c) s += s_att[c] * fus_w1[t * 128 + c];
    s_h[t] = fmaxf(s, 0.f);
  }
  if (t == 127) {
    float m = fmaxf(fmaxf(s_k[0], s_k[1]), fmaxf(s_k[2], s_k[3]));
    float e0 = expf(s_k[0] - m), e1 = expf(s_k[1] - m);
    float e2 = expf(s_k[2] - m), e3 = expf(s_k[3] - m);
    float inv = 1.f / (e0 + e1 + e2 + e3);
    s_k[0] = e0 * inv; s_k[1] = e1 * inv; s_k[2] = e2 * inv; s_k[3] = e3 * inv;
  }
  __syncthreads();

  {
    float s = fus_b2[t];
    for (int j = 0; j < 8; ++j) s += s_h[j] * fus_w2[t * 8 + j];
    s_att2[t] = 1.f / (1.f + expf(-s));
  }
  __syncthreads();

  if (t < 2) {
    float s = 0.f;
    for (int c = 0; c < 64; ++c) s += s_att2[t * 64 + c];
    s_red[t] = s;
  }
  __syncthreads();
  if (t == 0) {
    float m = fmaxf(s_red[0], s_red[1]);
    float e1 = expf(s_red[0] - m), e2 = expf(s_red[1] - m);
    float inv = 1.f / (e1 + e2);
    s_w12[0] = e1 * inv;
    s_w12[1] = e2 * inv;
  }
  __syncthreads();

  if (t < 64) {
    o_cin[b * 64 + t]  = s_w12[0] * s_att[t];
    o_cout[b * 64 + t] = s_w12[1] * s_att[64 + t];
  }
  if (t < 9) o_sp9[b * 9 + t] = s_sp[t];
  if (t < 4) o_k4[b * 4 + t] = s_k[t];
}

// ---------------- 3) fused per-sample weight -> bf16 [b][pq][o][i] ----------------
__global__ __launch_bounds__(256) void wf_kernel(const float* __restrict__ weight,
                                                 const float* __restrict__ cin,
                                                 const float* __restrict__ cout_,
                                                 const float* __restrict__ sp9,
                                                 const float* __restrict__ k4,
                                                 ushort_t* __restrict__ wfb) {
  const int bo = blockIdx.x;              // b*64 + o
  const int b = bo >> 6, o = bo & 63;
  const float co = cout_[b * 64 + o];
  const float k0 = k4[b * 4 + 0], k1 = k4[b * 4 + 1];
  const float k2 = k4[b * 4 + 2], k3 = k4[b * 4 + 3];
  for (int idx = threadIdx.x; idx < 576; idx += 256) {
    const int pq = idx >> 6, i = idx & 63;
    const size_t wi = ((size_t)o * 64 + i) * 9 + pq;
    float s = k0 * weight[wi] + k1 * weight[36864 + wi] +
              k2 * weight[73728 + wi] + k3 * weight[110592 + wi];
    float v = co * sp9[b * 9 + pq] * cin[b * 64 + i] * s;
    wfb[((size_t)(b * 9 + pq) * 64 + o) * 64 + i] = (ushort_t)f2bf(v);
  }
}

// ---------------- 4) implicit-GEMM conv, dbuf, 64-oc waves, static regs ----------------
// block: 512 thr (8 waves), one batch, 4 output rows x 128 cols, all 64 oc.
// wave (wid): row = wid>>1, col-half = wid&1; acc = 2 of x 2 nt f32x16 (64 AGPR).
// Each ds_read_b128 feeds 2 MFMAs (af0: oc0-31, af1: oc32-63).
// LDS: 2 x [pix=6*136][16 ci] bf16, XOR swizzle byte^=(((pix>>2)&7)<<4).
#define CONV_BUF_BYTES 26112
__global__ __launch_bounds__(512, 4) void conv_kernel(const float* __restrict__ x,
                                                      const ushort_t* __restrict__ wfb,
                                                      float* __restrict__ out) {
  const int b  = blockIdx.x >> 5;
  const int h0 = (blockIdx.x & 31) << 2;
  const int tid = threadIdx.x;
  const int lane = tid & 63;
  const int wid = tid >> 6;
  const int rw    = wid >> 1;           // wave's output row (0..3)
  const int nhalf = wid & 1;            // wave's 64-col half
  const int l31 = lane & 31;
  const int hi  = lane >> 5;

  __shared__ __align__(16) short sx[2 * 816 * 16];   // 52224 B

  f32x16 acc00, acc01, acc10, acc11;    // [of][nt], all-static
#pragma unroll
  for (int r = 0; r < 16; ++r) { acc00[r] = 0.f; acc01[r] = 0.f; acc10[r] = 0.f; acc11[r] = 0.f; }

  const ushort_t* wfb_b = wfb + (size_t)b * 9 * 64 * 64;

  // staging: 408 threads; thread owns (oct=tid/204, slot: sr=rem/34, sc=rem%34)
  const bool sact = tid < 408;
  int so = 0, sr = 0, sc = 0;
  if (sact) { so = tid / 204; const int rem = tid % 204; sr = rem / 34; sc = rem % 34; }
  const int gr  = h0 - 1 + sr;
  const int gcb = sc * 4 - 4;
  const bool inb = sact && ((unsigned)gr < 128u) && ((unsigned)gcb < 128u);
  const int pixb = sr * 136 + sc * 4;
  const int key = ((pixb >> 2) & 7) << 4;
  const int oct16 = so * 16;
  const float* xrow = x + ((size_t)b * 64) * 16384 + gr * 128 + gcb;

  float4 v0, v1, v2, v3, v4, v5, v6, v7;

#define LOADV(C0)                                              \
  do {                                                         \
    v0 = *(const float4*)(xrow + (size_t)((C0) + 0) * 16384);  \
    v1 = *(const float4*)(xrow + (size_t)((C0) + 1) * 16384);  \
    v2 = *(const float4*)(xrow + (size_t)((C0) + 2) * 16384);  \
    v3 = *(const float4*)(xrow + (size_t)((C0) + 3) * 16384);  \
    v4 = *(const float4*)(xrow + (size_t)((C0) + 4) * 16384);  \
    v5 = *(const float4*)(xrow + (size_t)((C0) + 5) * 16384);  \
    v6 = *(const float4*)(xrow + (size_t)((C0) + 6) * 16384);  \
    v7 = *(const float4*)(xrow + (size_t)((C0) + 7) * 16384);  \
  } while (0)

#define PKW(J, FLD, BUFB)                                                     \
  do {                                                                        \
    uint4 u;                                                                  \
    u.x = pk2(v0.FLD, v1.FLD);                                                \
    u.y = pk2(v2.FLD, v3.FLD);                                                \
    u.z = pk2(v4.FLD, v5.FLD);                                                \
    u.w = pk2(v6.FLD, v7.FLD);                                                \
    *(uint4*)((char*)sx + (BUFB) + ((((pixb + (J)) * 32) + oct16) ^ key)) = u;\
  } while (0)

#define PACK_WRITE(BUFB) \
  do { PKW(0, x, BUFB); PKW(1, y, BUFB); PKW(2, z, BUFB); PKW(3, w, BUFB); } while (0)

  // zero-fill OOB slots once (both buffers)
  if (sact && !inb) {
    const uint4 z = make_uint4(0u, 0u, 0u, 0u);
#pragma unroll
    for (int buf = 0; buf < 2; ++buf)
#pragma unroll
      for (int j = 0; j < 4; ++j)
        *(uint4*)((char*)sx + buf * CONV_BUF_BYTES +
                  ((((pixb + j) * 32) + oct16) ^ key)) = z;
  }

  // prologue: chunk 0 -> buf 0
  if (inb) {
    LOADV(so * 8);
    PACK_WRITE(0);
  }
  __syncthreads();

#pragma unroll
  for (int ch = 0; ch < 4; ++ch) {
    const int c0 = ch * 16;
    if (ch < 3 && inb) LOADV(c0 + 16 + so * 8);   // early-issue next chunk
    const int bufb = (ch & 1) * CONV_BUF_BYTES;
#pragma unroll
    for (int p = 0; p < 3; ++p) {
#pragma unroll
      for (int q = 0; q < 3; ++q) {
        const int tap = p * 3 + q;
        bf16x8 af0 = *(const bf16x8*)(wfb_b + (tap * 64 + l31) * 64 + c0 + hi * 8);
        bf16x8 af1 = *(const bf16x8*)(wfb_b + (tap * 64 + 32 + l31) * 64 + c0 + hi * 8);
        {
          const int pix = (rw + p) * 136 + 3 + q + nhalf * 64 + l31;
          const int boff = bufb + ((pix * 32 + hi * 16) ^ (((pix >> 2) & 7) << 4));
          bf16x8 bf = *(const bf16x8*)((const char*)sx + boff);
          acc00 = __builtin_amdgcn_mfma_f32_32x32x16_bf16(af0, bf, acc00, 0, 0, 0);
          acc10 = __builtin_amdgcn_mfma_f32_32x32x16_bf16(af1, bf, acc10, 0, 0, 0);
        }
        {
          const int pix = (rw + p) * 136 + 3 + q + nhalf * 64 + 32 + l31;
          const int boff = bufb + ((pix * 32 + hi * 16) ^ (((pix >> 2) & 7) << 4));
          bf16x8 bf = *(const bf16x8*)((const char*)sx + boff);
          acc01 = __builtin_amdgcn_mfma_f32_32x32x16_bf16(af0, bf, acc01, 0, 0, 0);
          acc11 = __builtin_amdgcn_mfma_f32_32x32x16_bf16(af1, bf, acc11, 0, 0, 0);
        }
      }
    }
    if (ch < 3) {
      if (inb) PACK_WRITE(((ch + 1) & 1) * CONV_BUF_BYTES);
      __syncthreads();
    }
  }

  const int h = h0 + rw;
#define STORE_ACC(ACC, OFB, NT)                                                \
  do {                                                                         \
    const int col = nhalf * 64 + (NT) * 32 + l31;                              \
    _Pragma("unroll") for (int reg = 0; reg < 16; ++reg) {                     \
      const int o = (OFB) + (reg & 3) + ((reg >> 2) << 3) + (hi << 2);         \
      out[(((size_t)(b * 64 + o)) * 128 + h) * 128 + col] = (ACC)[reg];        \
    }                                                                          \
  } while (0)

  STORE_ACC(acc00, 0, 0);
  STORE_ACC(acc01, 0, 1);
  STORE_ACC(acc10, 32, 0);
  STORE_ACC(acc11, 32, 1);
#undef STORE_ACC
#undef PACK_WRITE
#undef PKW
#undef LOADV
}

extern "C" void kernel_launch(void* const* d_in, const int* in_sizes, int n_in,
                              void* d_out, int out_size, void* d_ws, size_t ws_size,
                              hipStream_t stream) {
  const float* x      = (const float*)d_in[0];
  const float* fc_w   = (const float*)d_in[1];
  const float* ch_w   = (const float*)d_in[2];
  const float* ch_b   = (const float*)d_in[3];
  const float* f_w    = (const float*)d_in[4];
  const float* f_b    = (const float*)d_in[5];
  const float* sp_w   = (const float*)d_in[6];
  const float* sp_b   = (const float*)d_in[7];
  const float* k_w    = (const float*)d_in[8];
  const float* k_b    = (const float*)d_in[9];
  const float* fus_w1 = (const float*)d_in[10];
  const float* fus_b1 = (const float*)d_in[11];
  const float* fus_w2 = (const float*)d_in[12];
  const float* fus_b2 = (const float*)d_in[13];
  const float* weight = (const float*)d_in[14];
  float* ws  = (float*)d_ws;
  float* out = (float*)d_out;
  ushort_t* wfb = (ushort_t*)(ws + WS_WF);

  pool_kernel<<<2048, 256, 0, stream>>>(x, ws + WS_POOLED);
  att_kernel<<<32, 128, 0, stream>>>(ws + WS_POOLED, fc_w, ch_w, ch_b, f_w, f_b,
                                     sp_w, sp_b, k_w, k_b, fus_w1, fus_b1,
                                     fus_w2, fus_b2, ws + WS_CIN, ws + WS_COUT,
                                     ws + WS_SP9, ws + WS_K4);
  wf_kernel<<<2048, 256, 0, stream>>>(weight, ws + WS_CIN, ws + WS_COUT,
                                      ws + WS_SP9, ws + WS_K4, wfb);
  conv_kernel<<<1024, 512, 0, stream>>>(x, wfb, out);
}